// Round 1
// baseline (179.501 us; speedup 1.0000x reference)
//
#include <hip/hip_runtime.h>
#include <stdint.h>

typedef __bf16 bf16_t;
typedef __bf16 bf16x8 __attribute__((ext_vector_type(8)));
typedef float f32x4 __attribute__((ext_vector_type(4)));

#define B_ROWS 8192
#define D_DIM  512

// ---------------------------------------------------------------------------
// Kernel 1: per-row normalize (fp32 -> bf16) + cos(anchor, positive)
// One block per row; 256 threads handle 512 elements (2 each).
// ---------------------------------------------------------------------------
__global__ __launch_bounds__(256) void norm_kernel(
    const float* __restrict__ anchor, const float* __restrict__ positive,
    bf16_t* __restrict__ a_bf, bf16_t* __restrict__ p_bf,
    float* __restrict__ cos_ap)
{
  const int r = blockIdx.x;
  const int t = threadIdx.x;
  const float* a = anchor   + (size_t)r * D_DIM;
  const float* p = positive + (size_t)r * D_DIM;

  float a0 = a[t], a1 = a[t + 256];
  float p0 = p[t], p1 = p[t + 256];

  float sa = a0 * a0 + a1 * a1;
  float sp = p0 * p0 + p1 * p1;
  float dp = a0 * p0 + a1 * p1;

  // wave(64) reduce, then cross-wave via LDS
  for (int off = 32; off > 0; off >>= 1) {
    sa += __shfl_down(sa, off);
    sp += __shfl_down(sp, off);
    dp += __shfl_down(dp, off);
  }
  __shared__ float red[3][4];
  const int wave = t >> 6, lane = t & 63;
  if (lane == 0) { red[0][wave] = sa; red[1][wave] = sp; red[2][wave] = dp; }
  __syncthreads();
  sa = red[0][0] + red[0][1] + red[0][2] + red[0][3];
  sp = red[1][0] + red[1][1] + red[1][2] + red[1][3];
  dp = red[2][0] + red[2][1] + red[2][2] + red[2][3];

  const float na = sqrtf(sa), np = sqrtf(sp);
  const float ia = 1.0f / na, ip = 1.0f / np;

  bf16_t* ab = a_bf + (size_t)r * D_DIM;
  bf16_t* pb = p_bf + (size_t)r * D_DIM;
  ab[t]       = (bf16_t)(a0 * ia);
  ab[t + 256] = (bf16_t)(a1 * ia);
  pb[t]       = (bf16_t)(p0 * ip);
  pb[t + 256] = (bf16_t)(p1 * ip);

  if (t == 0) cos_ap[r] = dp / fmaxf(na * np, 1e-8f);
}

// ---------------------------------------------------------------------------
// global -> LDS direct load, 16B per lane. Dest is wave-uniform base;
// lane i lands at base + i*16B (m104/m108). uintptr_t trick: global as(1) is
// flat-identical; LDS generic low 32 bits are the LDS byte offset.
// ---------------------------------------------------------------------------
__device__ __forceinline__ void load16_to_lds(const void* g, void* l) {
  __builtin_amdgcn_global_load_lds(
      (__attribute__((address_space(1))) uint32_t*)(uintptr_t)(g),
      (__attribute__((address_space(3))) uint32_t*)(uintptr_t)(l),
      16, 0, 0);
}

// ---------------------------------------------------------------------------
// Kernel 2: 128x128 bf16 MFMA tile of sim = A_n * P_n^T, fused row-min
// epilogue (diagonal excluded). partial[colTile][row] gets the min over this
// block's 128 columns. Grid (64 rowTiles, 64 colTiles), 256 threads = 4 waves
// in a 2x2 wave grid; each wave owns a 64x64 region = 4x4 frags of 16x16x32.
// ---------------------------------------------------------------------------
__global__ __launch_bounds__(256) void simmin_kernel(
    const bf16_t* __restrict__ a_bf, const bf16_t* __restrict__ p_bf,
    float* __restrict__ partial)
{
  __shared__ __attribute__((aligned(16))) bf16_t Alds[128 * 32];
  __shared__ __attribute__((aligned(16))) bf16_t Plds[128 * 32];
  __shared__ float redmin[256];

  const int tid  = threadIdx.x;
  const int lane = tid & 63;
  const int wave = tid >> 6;
  const int waveM = wave >> 1, waveN = wave & 1;
  const int quad = lane >> 4;
  const int l15  = lane & 15;
  const int blockRow = blockIdx.x, blockCol = blockIdx.y;

  f32x4 acc[4][4];
  const f32x4 zero = {0.f, 0.f, 0.f, 0.f};
#pragma unroll
  for (int i = 0; i < 4; i++)
#pragma unroll
    for (int j = 0; j < 4; j++) acc[i][j] = zero;

  // staging: per 1KB chunk (64 lanes x 16B), lane i covers
  // row = chunk*16 + i/4, k = (i%4)*8 of the [128][32] tile
  const int srow = lane >> 2;
  const int skc  = (lane & 3) * 8;
  const bf16_t* aBase = a_bf + (size_t)(blockRow * 128) * D_DIM;
  const bf16_t* pBase = p_bf + (size_t)(blockCol * 128) * D_DIM;

  for (int k0 = 0; k0 < D_DIM; k0 += 32) {
#pragma unroll
    for (int c = 0; c < 2; c++) {
      const int chunk = wave * 2 + c;            // 0..7
      const int row   = chunk * 16 + srow;
      load16_to_lds(aBase + (size_t)row * D_DIM + k0 + skc, &Alds[chunk * 512]);
      load16_to_lds(pBase + (size_t)row * D_DIM + k0 + skc, &Plds[chunk * 512]);
    }
    __syncthreads();   // drain global_load_lds (vmcnt(0) before s_barrier)

    bf16x8 af[4], bfr[4];
#pragma unroll
    for (int mf = 0; mf < 4; mf++)
      af[mf] = *(const bf16x8*)&Alds[(waveM * 64 + mf * 16 + l15) * 32 + quad * 8];
#pragma unroll
    for (int nf = 0; nf < 4; nf++)
      bfr[nf] = *(const bf16x8*)&Plds[(waveN * 64 + nf * 16 + l15) * 32 + quad * 8];

#pragma unroll
    for (int mf = 0; mf < 4; mf++)
#pragma unroll
      for (int nf = 0; nf < 4; nf++)
        acc[mf][nf] = __builtin_amdgcn_mfma_f32_16x16x32_bf16(
            af[mf], bfr[nf], acc[mf][nf], 0, 0, 0);

    __syncthreads();   // all waves done reading LDS before next stage
  }

  // ---- fused epilogue: per-row min over this block's 128 cols, diag masked
  const int rowTileBase = blockRow * 128 + waveM * 64;
  const int colTileBase = blockCol * 128 + waveN * 64;

  float rm[4][4];
#pragma unroll
  for (int mf = 0; mf < 4; mf++)
#pragma unroll
    for (int r = 0; r < 4; r++) rm[mf][r] = 3.0e38f;

#pragma unroll
  for (int mf = 0; mf < 4; mf++) {
#pragma unroll
    for (int nf = 0; nf < 4; nf++) {
      const int col = colTileBase + nf * 16 + l15;
#pragma unroll
      for (int r = 0; r < 4; r++) {
        const int row = rowTileBase + mf * 16 + quad * 4 + r;
        const float v = acc[mf][nf][r];
        rm[mf][r] = (row == col) ? rm[mf][r] : fminf(rm[mf][r], v);
      }
    }
  }
  // butterfly min across the 16 col-lanes (lane bits 0..3); rows (lane>>4) fixed
#pragma unroll
  for (int d = 1; d < 16; d <<= 1)
#pragma unroll
    for (int mf = 0; mf < 4; mf++)
#pragma unroll
      for (int r = 0; r < 4; r++)
        rm[mf][r] = fminf(rm[mf][r], __shfl_xor(rm[mf][r], d));

  if (l15 == 0) {
#pragma unroll
    for (int mf = 0; mf < 4; mf++)
#pragma unroll
      for (int r = 0; r < 4; r++)
        redmin[waveN * 128 + waveM * 64 + mf * 16 + quad * 4 + r] = rm[mf][r];
  }
  __syncthreads();

  if (tid < 128) {
    const float m = fminf(redmin[tid], redmin[128 + tid]);
    partial[(size_t)blockCol * B_ROWS + blockRow * 128 + tid] = m;  // [64][8192]
  }
}

// ---------------------------------------------------------------------------
// Kernel 3: per-row min over 64 colTile partials, loss, mean into d_out.
// ---------------------------------------------------------------------------
__global__ __launch_bounds__(256) void finalize_kernel(
    const float* __restrict__ partial, const float* __restrict__ cos_ap,
    float* __restrict__ out)
{
  const int r = blockIdx.x * 256 + threadIdx.x;  // 32 blocks x 256 = 8192
  float m = 3.0e38f;
#pragma unroll 8
  for (int c = 0; c < 64; c++) m = fminf(m, partial[(size_t)c * B_ROWS + r]);
  float loss = fmaxf(0.0f, 1.0f + cos_ap[r] - m);

  for (int off = 32; off > 0; off >>= 1) loss += __shfl_down(loss, off);
  __shared__ float s[4];
  const int wave = threadIdx.x >> 6, lane = threadIdx.x & 63;
  if (lane == 0) s[wave] = loss;
  __syncthreads();
  if (threadIdx.x == 0) {
    const float t = (s[0] + s[1] + s[2] + s[3]) * (1.0f / (float)B_ROWS);
    atomicAdd(out, t);
  }
}

// ---------------------------------------------------------------------------
extern "C" void kernel_launch(void* const* d_in, const int* in_sizes, int n_in,
                              void* d_out, int out_size, void* d_ws, size_t ws_size,
                              hipStream_t stream) {
  const float* anchor   = (const float*)d_in[0];
  const float* positive = (const float*)d_in[1];

  char* ws = (char*)d_ws;
  bf16_t* a_bf   = (bf16_t*)(ws);                                  // 8 MB
  bf16_t* p_bf   = (bf16_t*)(ws + (8ull << 20));                   // 8 MB
  float*  cos_ap = (float*)(ws + (16ull << 20));                   // 32 KB
  float*  partial = (float*)(ws + (16ull << 20) + (64ull << 10));  // 2 MB
  float*  out = (float*)d_out;

  hipMemsetAsync(out, 0, sizeof(float), stream);  // d_out is poisoned each call
  norm_kernel<<<B_ROWS, 256, 0, stream>>>(anchor, positive, a_bf, p_bf, cos_ap);
  simmin_kernel<<<dim3(64, 64), 256, 0, stream>>>(a_bf, p_bf, partial);
  finalize_kernel<<<32, 256, 0, stream>>>(partial, cos_ap, out);
}

// Round 2
// 141.931 us; speedup vs baseline: 1.2647x; 1.2647x over previous
//
#include <hip/hip_runtime.h>
#include <stdint.h>

typedef int   i32x8 __attribute__((ext_vector_type(8)));
typedef float f32x4 __attribute__((ext_vector_type(4)));

#define B_ROWS 8192
#define D_DIM  512

// ---------------------------------------------------------------------------
// Kernel 1: per-row normalize (fp32 -> fp8 e4m3) + cos(anchor, positive).
// Wave per row: 4 rows/block, 2048 blocks. No LDS, no __syncthreads.
// Each lane owns 8 consecutive elements (two float4 loads).
// ---------------------------------------------------------------------------
__global__ __launch_bounds__(256) void norm_kernel(
    const float* __restrict__ anchor, const float* __restrict__ positive,
    uint32_t* __restrict__ a8, uint32_t* __restrict__ p8,
    float* __restrict__ cos_ap)
{
  const int wave = threadIdx.x >> 6, lane = threadIdx.x & 63;
  const int r = blockIdx.x * 4 + wave;

  const float4* av = (const float4*)(anchor   + (size_t)r * D_DIM) + lane * 2;
  const float4* pv = (const float4*)(positive + (size_t)r * D_DIM) + lane * 2;
  float4 a0 = av[0], a1 = av[1];
  float4 p0 = pv[0], p1 = pv[1];

  float sa = a0.x*a0.x + a0.y*a0.y + a0.z*a0.z + a0.w*a0.w
           + a1.x*a1.x + a1.y*a1.y + a1.z*a1.z + a1.w*a1.w;
  float sp = p0.x*p0.x + p0.y*p0.y + p0.z*p0.z + p0.w*p0.w
           + p1.x*p1.x + p1.y*p1.y + p1.z*p1.z + p1.w*p1.w;
  float dp = a0.x*p0.x + a0.y*p0.y + a0.z*p0.z + a0.w*p0.w
           + a1.x*p1.x + a1.y*p1.y + a1.z*p1.z + a1.w*p1.w;

#pragma unroll
  for (int d = 1; d < 64; d <<= 1) {
    sa += __shfl_xor(sa, d);
    sp += __shfl_xor(sp, d);
    dp += __shfl_xor(dp, d);
  }

  const float na = sqrtf(sa), np = sqrtf(sp);
  const float ia = 1.0f / na, ip = 1.0f / np;

  // pack 8 normalized values -> 8 fp8 bytes (2 dwords) per lane
  float na0 = a0.x*ia, na1 = a0.y*ia, na2 = a0.z*ia, na3 = a0.w*ia;
  float na4 = a1.x*ia, na5 = a1.y*ia, na6 = a1.z*ia, na7 = a1.w*ia;
  float np0 = p0.x*ip, np1 = p0.y*ip, np2 = p0.z*ip, np3 = p0.w*ip;
  float np4 = p1.x*ip, np5 = p1.y*ip, np6 = p1.z*ip, np7 = p1.w*ip;

  uint32_t aw0 = __builtin_amdgcn_cvt_pk_fp8_f32(na0, na1, 0,  false);
  aw0          = __builtin_amdgcn_cvt_pk_fp8_f32(na2, na3, aw0, true);
  uint32_t aw1 = __builtin_amdgcn_cvt_pk_fp8_f32(na4, na5, 0,  false);
  aw1          = __builtin_amdgcn_cvt_pk_fp8_f32(na6, na7, aw1, true);
  uint32_t pw0 = __builtin_amdgcn_cvt_pk_fp8_f32(np0, np1, 0,  false);
  pw0          = __builtin_amdgcn_cvt_pk_fp8_f32(np2, np3, pw0, true);
  uint32_t pw1 = __builtin_amdgcn_cvt_pk_fp8_f32(np4, np5, 0,  false);
  pw1          = __builtin_amdgcn_cvt_pk_fp8_f32(np6, np7, pw1, true);

  ((uint2*)a8)[(size_t)r * 64 + lane] = make_uint2(aw0, aw1);
  ((uint2*)p8)[(size_t)r * 64 + lane] = make_uint2(pw0, pw1);

  if (lane == 0) cos_ap[r] = dp / fmaxf(na * np, 1e-8f);
}

// ---------------------------------------------------------------------------
// global -> LDS direct load, 16B per lane (dest = wave-uniform base + lane*16).
// ---------------------------------------------------------------------------
__device__ __forceinline__ void load16_to_lds(const void* g, void* l) {
  __builtin_amdgcn_global_load_lds(
      (__attribute__((address_space(1))) uint32_t*)(uintptr_t)(g),
      (__attribute__((address_space(3))) uint32_t*)(uintptr_t)(l),
      16, 0, 0);
}

// ---------------------------------------------------------------------------
// Kernel 2: 128x128 fp8 (e4m3) MX-MFMA tile of sim = A_n * P_n^T with
// scale = 1.0 (0x7F e8m0), fused diagonal-masked row-min epilogue.
// BK=128 (one 16x16x128 mfma in K per frag), 4 K-iterations.
// LDS layout XOR-swizzled: row r holds global k-slot g at slot g^(r&7)
// (slot = 16B). Staging fetches pre-swizzled so the LDS side stays
// contiguous (global_load_lds constraint); fragment reads then hit all 32
// banks with only 2-way aliasing (free).
// ---------------------------------------------------------------------------
__global__ __launch_bounds__(256) void simmin_kernel(
    const uint8_t* __restrict__ a8, const uint8_t* __restrict__ p8,
    float* __restrict__ partial)
{
  __shared__ __attribute__((aligned(16))) uint8_t Alds[128 * 128];
  __shared__ __attribute__((aligned(16))) uint8_t Plds[128 * 128];
  __shared__ float redmin[256];

  const int tid  = threadIdx.x;
  const int lane = tid & 63;
  const int wave = tid >> 6;
  const int waveM = wave >> 1, waveN = wave & 1;
  const int quad = lane >> 4;
  const int l15  = lane & 15;
  const int blockRow = blockIdx.x, blockCol = blockIdx.y;

  f32x4 acc[4][4];
  const f32x4 zero = {0.f, 0.f, 0.f, 0.f};
#pragma unroll
  for (int i = 0; i < 4; i++)
#pragma unroll
    for (int j = 0; j < 4; j++) acc[i][j] = zero;

  // staging: chunk = 8 rows x 128B. Lane i: row = i/8, swizzled k-slot.
  const int srow = lane >> 3;               // row within chunk
  const int sk   = (lane & 7) ^ srow;       // pre-swizzled global k-slot
  const uint8_t* aBase = a8 + (size_t)(blockRow * 128) * D_DIM;
  const uint8_t* pBase = p8 + (size_t)(blockCol * 128) * D_DIM;

  for (int k0 = 0; k0 < D_DIM; k0 += 128) {
#pragma unroll
    for (int c = 0; c < 4; c++) {
      const int chunk = wave * 4 + c;       // 0..15
      const size_t goff = (size_t)(chunk * 8 + srow) * D_DIM + k0 + sk * 16;
      load16_to_lds(aBase + goff, &Alds[chunk * 1024]);
      load16_to_lds(pBase + goff, &Plds[chunk * 1024]);
    }
    __syncthreads();

    i32x8 af[4], bfr[4];
#pragma unroll
    for (int mf = 0; mf < 4; mf++) {
      const int r = waveM * 64 + mf * 16 + l15;
      const int rx = r & 7;
      const int4 lo = *(const int4*)&Alds[r * 128 + (((quad * 2 + 0) ^ rx) * 16)];
      const int4 hi = *(const int4*)&Alds[r * 128 + (((quad * 2 + 1) ^ rx) * 16)];
      af[mf] = (i32x8){lo.x, lo.y, lo.z, lo.w, hi.x, hi.y, hi.z, hi.w};
    }
#pragma unroll
    for (int nf = 0; nf < 4; nf++) {
      const int r = waveN * 64 + nf * 16 + l15;
      const int rx = r & 7;
      const int4 lo = *(const int4*)&Plds[r * 128 + (((quad * 2 + 0) ^ rx) * 16)];
      const int4 hi = *(const int4*)&Plds[r * 128 + (((quad * 2 + 1) ^ rx) * 16)];
      bfr[nf] = (i32x8){lo.x, lo.y, lo.z, lo.w, hi.x, hi.y, hi.z, hi.w};
    }

#pragma unroll
    for (int mf = 0; mf < 4; mf++)
#pragma unroll
      for (int nf = 0; nf < 4; nf++)
        acc[mf][nf] = __builtin_amdgcn_mfma_scale_f32_16x16x128_f8f6f4(
            af[mf], bfr[nf], acc[mf][nf],
            0, 0,                 // cbsz=fp8(e4m3) A, blgp=fp8(e4m3) B
            0, 0x7F7F7F7F,        // scale A opsel, scale A (2^0)
            0, 0x7F7F7F7F);       // scale B opsel, scale B (2^0)

    __syncthreads();
  }

  // ---- fused epilogue: per-row min over this block's 128 cols, diag masked
  const int rowTileBase = blockRow * 128 + waveM * 64;
  const int colTileBase = blockCol * 128 + waveN * 64;

  float rm[4][4];
#pragma unroll
  for (int mf = 0; mf < 4; mf++)
#pragma unroll
    for (int r = 0; r < 4; r++) rm[mf][r] = 3.0e38f;

#pragma unroll
  for (int mf = 0; mf < 4; mf++) {
#pragma unroll
    for (int nf = 0; nf < 4; nf++) {
      const int col = colTileBase + nf * 16 + l15;
#pragma unroll
      for (int r = 0; r < 4; r++) {
        const int row = rowTileBase + mf * 16 + quad * 4 + r;
        const float v = acc[mf][nf][r];
        rm[mf][r] = (row == col) ? rm[mf][r] : fminf(rm[mf][r], v);
      }
    }
  }
#pragma unroll
  for (int d = 1; d < 16; d <<= 1)
#pragma unroll
    for (int mf = 0; mf < 4; mf++)
#pragma unroll
      for (int r = 0; r < 4; r++)
        rm[mf][r] = fminf(rm[mf][r], __shfl_xor(rm[mf][r], d));

  if (l15 == 0) {
#pragma unroll
    for (int mf = 0; mf < 4; mf++)
#pragma unroll
      for (int r = 0; r < 4; r++)
        redmin[waveN * 128 + waveM * 64 + mf * 16 + quad * 4 + r] = rm[mf][r];
  }
  __syncthreads();

  if (tid < 128) {
    const float m = fminf(redmin[tid], redmin[128 + tid]);
    partial[(size_t)blockCol * B_ROWS + blockRow * 128 + tid] = m;  // [64][8192]
  }
}

// ---------------------------------------------------------------------------
// Kernel 3: per-row min over 64 colTile partials, loss, mean into d_out.
// ---------------------------------------------------------------------------
__global__ __launch_bounds__(256) void finalize_kernel(
    const float* __restrict__ partial, const float* __restrict__ cos_ap,
    float* __restrict__ out)
{
  const int r = blockIdx.x * 256 + threadIdx.x;  // 32 blocks x 256 = 8192
  float m = 3.0e38f;
#pragma unroll 8
  for (int c = 0; c < 64; c++) m = fminf(m, partial[(size_t)c * B_ROWS + r]);
  float loss = fmaxf(0.0f, 1.0f + cos_ap[r] - m);

  for (int off = 32; off > 0; off >>= 1) loss += __shfl_down(loss, off);
  __shared__ float s[4];
  const int wave = threadIdx.x >> 6, lane = threadIdx.x & 63;
  if (lane == 0) s[wave] = loss;
  __syncthreads();
  if (threadIdx.x == 0) {
    const float t = (s[0] + s[1] + s[2] + s[3]) * (1.0f / (float)B_ROWS);
    atomicAdd(out, t);
  }
}

// ---------------------------------------------------------------------------
extern "C" void kernel_launch(void* const* d_in, const int* in_sizes, int n_in,
                              void* d_out, int out_size, void* d_ws, size_t ws_size,
                              hipStream_t stream) {
  const float* anchor   = (const float*)d_in[0];
  const float* positive = (const float*)d_in[1];

  char* ws = (char*)d_ws;
  uint32_t* a8     = (uint32_t*)(ws);                               // 4 MB
  uint32_t* p8     = (uint32_t*)(ws + (4ull << 20));                // 4 MB
  float*    cos_ap = (float*)(ws + (8ull << 20));                   // 32 KB
  float*    partial = (float*)(ws + (8ull << 20) + (64ull << 10));  // 2 MB
  float*    out = (float*)d_out;

  hipMemsetAsync(out, 0, sizeof(float), stream);
  norm_kernel<<<B_ROWS / 4, 256, 0, stream>>>(anchor, positive, a8, p8, cos_ap);
  simmin_kernel<<<dim3(64, 64), 256, 0, stream>>>((const uint8_t*)a8,
                                                  (const uint8_t*)p8, partial);
  finalize_kernel<<<32, 256, 0, stream>>>(partial, cos_ap, out);
}

// Round 3
// 124.627 us; speedup vs baseline: 1.4403x; 1.1388x over previous
//
#include <hip/hip_runtime.h>
#include <stdint.h>

typedef int   i32x8 __attribute__((ext_vector_type(8)));
typedef float f32x4 __attribute__((ext_vector_type(4)));

#define B_ROWS 8192
#define D_DIM  512

// monotone float<->uint encoding: enc order == float order (so uint atomicMin
// == float min). f>=0: set sign bit; f<0: bitwise NOT.
__device__ __forceinline__ uint32_t enc_f32(float f) {
  uint32_t s = __float_as_uint(f);
  return (s & 0x80000000u) ? ~s : (s | 0x80000000u);
}
__device__ __forceinline__ float dec_f32(uint32_t e) {
  uint32_t s = (e & 0x80000000u) ? (e ^ 0x80000000u) : ~e;
  return __uint_as_float(s);
}

// ---------------------------------------------------------------------------
// Kernel 1: per-row normalize (fp32 -> fp8 e4m3) + cos(anchor, positive).
// Wave per row. Also inits minenc[r] = +inf encoding (replaces a memset node).
// ---------------------------------------------------------------------------
__global__ __launch_bounds__(256) void norm_kernel(
    const float* __restrict__ anchor, const float* __restrict__ positive,
    uint32_t* __restrict__ a8, uint32_t* __restrict__ p8,
    float* __restrict__ cos_ap, uint32_t* __restrict__ minenc)
{
  const int wave = threadIdx.x >> 6, lane = threadIdx.x & 63;
  const int r = blockIdx.x * 4 + wave;

  const float4* av = (const float4*)(anchor   + (size_t)r * D_DIM) + lane * 2;
  const float4* pv = (const float4*)(positive + (size_t)r * D_DIM) + lane * 2;
  float4 a0 = av[0], a1 = av[1];
  float4 p0 = pv[0], p1 = pv[1];

  float sa = a0.x*a0.x + a0.y*a0.y + a0.z*a0.z + a0.w*a0.w
           + a1.x*a1.x + a1.y*a1.y + a1.z*a1.z + a1.w*a1.w;
  float sp = p0.x*p0.x + p0.y*p0.y + p0.z*p0.z + p0.w*p0.w
           + p1.x*p1.x + p1.y*p1.y + p1.z*p1.z + p1.w*p1.w;
  float dp = a0.x*p0.x + a0.y*p0.y + a0.z*p0.z + a0.w*p0.w
           + a1.x*p1.x + a1.y*p1.y + a1.z*p1.z + a1.w*p1.w;

#pragma unroll
  for (int d = 1; d < 64; d <<= 1) {
    sa += __shfl_xor(sa, d);
    sp += __shfl_xor(sp, d);
    dp += __shfl_xor(dp, d);
  }

  const float na = sqrtf(sa), np = sqrtf(sp);
  const float ia = 1.0f / na, ip = 1.0f / np;

  float na0 = a0.x*ia, na1 = a0.y*ia, na2 = a0.z*ia, na3 = a0.w*ia;
  float na4 = a1.x*ia, na5 = a1.y*ia, na6 = a1.z*ia, na7 = a1.w*ia;
  float np0 = p0.x*ip, np1 = p0.y*ip, np2 = p0.z*ip, np3 = p0.w*ip;
  float np4 = p1.x*ip, np5 = p1.y*ip, np6 = p1.z*ip, np7 = p1.w*ip;

  uint32_t aw0 = __builtin_amdgcn_cvt_pk_fp8_f32(na0, na1, 0,  false);
  aw0          = __builtin_amdgcn_cvt_pk_fp8_f32(na2, na3, aw0, true);
  uint32_t aw1 = __builtin_amdgcn_cvt_pk_fp8_f32(na4, na5, 0,  false);
  aw1          = __builtin_amdgcn_cvt_pk_fp8_f32(na6, na7, aw1, true);
  uint32_t pw0 = __builtin_amdgcn_cvt_pk_fp8_f32(np0, np1, 0,  false);
  pw0          = __builtin_amdgcn_cvt_pk_fp8_f32(np2, np3, pw0, true);
  uint32_t pw1 = __builtin_amdgcn_cvt_pk_fp8_f32(np4, np5, 0,  false);
  pw1          = __builtin_amdgcn_cvt_pk_fp8_f32(np6, np7, pw1, true);

  ((uint2*)a8)[(size_t)r * 64 + lane] = make_uint2(aw0, aw1);
  ((uint2*)p8)[(size_t)r * 64 + lane] = make_uint2(pw0, pw1);

  if (lane == 0) {
    cos_ap[r] = dp / fmaxf(na * np, 1e-8f);
    minenc[r] = 0xFFFFFFFFu;   // +inf in monotone encoding
  }
}

// ---------------------------------------------------------------------------
// global -> LDS direct load, 16B per lane (dest = wave-uniform base + lane*16).
// ---------------------------------------------------------------------------
__device__ __forceinline__ void load16_to_lds(const void* g, void* l) {
  __builtin_amdgcn_global_load_lds(
      (__attribute__((address_space(1))) uint32_t*)(uintptr_t)(g),
      (__attribute__((address_space(3))) uint32_t*)(uintptr_t)(l),
      16, 0, 0);
}

// ---------------------------------------------------------------------------
// Kernel 2: 128x128 fp8 MX-MFMA tile of sim = A_n * P_n^T (scale=1.0), fused
// diagonal-masked row-min -> device atomicMin on encoded floats.
// Double-buffered LDS, ONE barrier per K-iter: stage tile k+1 is issued after
// the ds_reads of tile k and before the MFMAs, so the barrier's vmcnt(0)
// drain lands ~an MFMA-block after issue (latency hidden).
// ---------------------------------------------------------------------------
__global__ __launch_bounds__(256, 2) void simmin_kernel(
    const uint8_t* __restrict__ a8, const uint8_t* __restrict__ p8,
    uint32_t* __restrict__ minenc)
{
  __shared__ __attribute__((aligned(16))) uint8_t Alds[2][128 * 128];
  __shared__ __attribute__((aligned(16))) uint8_t Plds[2][128 * 128];
  __shared__ float redmin[256];

  const int tid  = threadIdx.x;
  const int lane = tid & 63;
  const int wave = tid >> 6;
  const int waveM = wave >> 1, waveN = wave & 1;
  const int quad = lane >> 4;
  const int l15  = lane & 15;
  const int blockRow = blockIdx.x, blockCol = blockIdx.y;

  f32x4 acc[4][4];
  const f32x4 zero = {0.f, 0.f, 0.f, 0.f};
#pragma unroll
  for (int i = 0; i < 4; i++)
#pragma unroll
    for (int j = 0; j < 4; j++) acc[i][j] = zero;

  // staging: chunk = 8 rows x 128B; lane i: row = i/8, XOR-swizzled k-slot
  // fetched pre-swizzled on the global side (LDS side must stay contiguous).
  const int srow = lane >> 3;
  const int sk   = (lane & 7) ^ srow;
  const uint8_t* aBase = a8 + (size_t)(blockRow * 128) * D_DIM;
  const uint8_t* pBase = p8 + (size_t)(blockCol * 128) * D_DIM;

  auto stage = [&](int k0, int buf) {
#pragma unroll
    for (int c = 0; c < 4; c++) {
      const int chunk = wave * 4 + c;       // 0..15
      const size_t goff = (size_t)(chunk * 8 + srow) * D_DIM + k0 + sk * 16;
      load16_to_lds(aBase + goff, &Alds[buf][chunk * 1024]);
      load16_to_lds(pBase + goff, &Plds[buf][chunk * 1024]);
    }
  };

  stage(0, 0);

#pragma unroll
  for (int k = 0; k < 4; k++) {
    __syncthreads();  // drains loads->buf[k&1]; also fences reads of buf from k-2
    const int buf = k & 1;

    i32x8 af[4], bfr[4];
#pragma unroll
    for (int mf = 0; mf < 4; mf++) {
      const int r = waveM * 64 + mf * 16 + l15;
      const int rx = r & 7;
      const int4 lo = *(const int4*)&Alds[buf][r * 128 + (((quad * 2 + 0) ^ rx) * 16)];
      const int4 hi = *(const int4*)&Alds[buf][r * 128 + (((quad * 2 + 1) ^ rx) * 16)];
      af[mf] = (i32x8){lo.x, lo.y, lo.z, lo.w, hi.x, hi.y, hi.z, hi.w};
    }
#pragma unroll
    for (int nf = 0; nf < 4; nf++) {
      const int r = waveN * 64 + nf * 16 + l15;
      const int rx = r & 7;
      const int4 lo = *(const int4*)&Plds[buf][r * 128 + (((quad * 2 + 0) ^ rx) * 16)];
      const int4 hi = *(const int4*)&Plds[buf][r * 128 + (((quad * 2 + 1) ^ rx) * 16)];
      bfr[nf] = (i32x8){lo.x, lo.y, lo.z, lo.w, hi.x, hi.y, hi.z, hi.w};
    }

    if (k < 3) stage((k + 1) * 128, (k + 1) & 1);  // prefetch next tile

#pragma unroll
    for (int mf = 0; mf < 4; mf++)
#pragma unroll
      for (int nf = 0; nf < 4; nf++)
        acc[mf][nf] = __builtin_amdgcn_mfma_scale_f32_16x16x128_f8f6f4(
            af[mf], bfr[nf], acc[mf][nf],
            0, 0,                 // cbsz=fp8(e4m3) A, blgp=fp8(e4m3) B
            0, 0x7F7F7F7F,        // scale A (2^0)
            0, 0x7F7F7F7F);       // scale B (2^0)
  }

  // ---- fused epilogue: per-row min over this block's 128 cols, diag masked
  const int rowTileBase = blockRow * 128 + waveM * 64;
  const int colTileBase = blockCol * 128 + waveN * 64;

  float rm[4][4];
#pragma unroll
  for (int mf = 0; mf < 4; mf++)
#pragma unroll
    for (int r = 0; r < 4; r++) rm[mf][r] = 3.0e38f;

#pragma unroll
  for (int mf = 0; mf < 4; mf++) {
#pragma unroll
    for (int nf = 0; nf < 4; nf++) {
      const int col = colTileBase + nf * 16 + l15;
#pragma unroll
      for (int r = 0; r < 4; r++) {
        const int row = rowTileBase + mf * 16 + quad * 4 + r;
        const float v = acc[mf][nf][r];
        rm[mf][r] = (row == col) ? rm[mf][r] : fminf(rm[mf][r], v);
      }
    }
  }
#pragma unroll
  for (int d = 1; d < 16; d <<= 1)
#pragma unroll
    for (int mf = 0; mf < 4; mf++)
#pragma unroll
      for (int r = 0; r < 4; r++)
        rm[mf][r] = fminf(rm[mf][r], __shfl_xor(rm[mf][r], d));

  if (l15 == 0) {
#pragma unroll
    for (int mf = 0; mf < 4; mf++)
#pragma unroll
      for (int r = 0; r < 4; r++)
        redmin[waveN * 128 + waveM * 64 + mf * 16 + quad * 4 + r] = rm[mf][r];
  }
  __syncthreads();

  if (tid < 128) {
    const float m = fminf(redmin[tid], redmin[128 + tid]);
    atomicMin(&minenc[blockRow * 128 + tid], enc_f32(m));  // device-scope
  }
}

// ---------------------------------------------------------------------------
// Kernel 3: single block — decode row-mins, loss, mean, plain store (no
// atomics, no memset needed).
// ---------------------------------------------------------------------------
__global__ __launch_bounds__(256) void finalize_kernel(
    const uint32_t* __restrict__ minenc, const float* __restrict__ cos_ap,
    float* __restrict__ out)
{
  float sum = 0.0f;
#pragma unroll 8
  for (int r = threadIdx.x; r < B_ROWS; r += 256)
    sum += fmaxf(0.0f, 1.0f + cos_ap[r] - dec_f32(minenc[r]));

#pragma unroll
  for (int d = 1; d < 64; d <<= 1) sum += __shfl_xor(sum, d);
  __shared__ float s[4];
  if ((threadIdx.x & 63) == 0) s[threadIdx.x >> 6] = sum;
  __syncthreads();
  if (threadIdx.x == 0)
    out[0] = (s[0] + s[1] + s[2] + s[3]) * (1.0f / (float)B_ROWS);
}

// ---------------------------------------------------------------------------
extern "C" void kernel_launch(void* const* d_in, const int* in_sizes, int n_in,
                              void* d_out, int out_size, void* d_ws, size_t ws_size,
                              hipStream_t stream) {
  const float* anchor   = (const float*)d_in[0];
  const float* positive = (const float*)d_in[1];

  char* ws = (char*)d_ws;
  uint32_t* a8     = (uint32_t*)(ws);                                // 4 MB
  uint32_t* p8     = (uint32_t*)(ws + (4ull << 20));                 // 4 MB
  float*    cos_ap = (float*)(ws + (8ull << 20));                    // 32 KB
  uint32_t* minenc = (uint32_t*)(ws + (8ull << 20) + (32ull << 10)); // 32 KB
  float*    out = (float*)d_out;

  norm_kernel<<<B_ROWS / 4, 256, 0, stream>>>(anchor, positive, a8, p8,
                                              cos_ap, minenc);
  simmin_kernel<<<dim3(64, 64), 256, 0, stream>>>((const uint8_t*)a8,
                                                  (const uint8_t*)p8, minenc);
  finalize_kernel<<<1, 256, 0, stream>>>(minenc, cos_ap, out);
}

// Round 4
// 124.224 us; speedup vs baseline: 1.4450x; 1.0032x over previous
//
#include <hip/hip_runtime.h>
#include <stdint.h>

typedef int   i32x8 __attribute__((ext_vector_type(8)));
typedef float f32x4 __attribute__((ext_vector_type(4)));

#define B_ROWS 8192
#define D_DIM  512

// monotone float<->uint encoding: enc order == float order (so uint atomicMin
// == float min). f>=0: set sign bit; f<0: bitwise NOT.
__device__ __forceinline__ uint32_t enc_f32(float f) {
  uint32_t s = __float_as_uint(f);
  return (s & 0x80000000u) ? ~s : (s | 0x80000000u);
}
__device__ __forceinline__ float dec_f32(uint32_t e) {
  uint32_t s = (e & 0x80000000u) ? (e ^ 0x80000000u) : ~e;
  return __uint_as_float(s);
}

// ---------------------------------------------------------------------------
// Kernel 1: per-row normalize (fp32 -> fp8 e4m3) + cos(anchor, positive).
// Wave per row. Also inits minenc[r] = +inf encoding (replaces a memset node).
// ---------------------------------------------------------------------------
__global__ __launch_bounds__(256) void norm_kernel(
    const float* __restrict__ anchor, const float* __restrict__ positive,
    uint32_t* __restrict__ a8, uint32_t* __restrict__ p8,
    float* __restrict__ cos_ap, uint32_t* __restrict__ minenc)
{
  const int wave = threadIdx.x >> 6, lane = threadIdx.x & 63;
  const int r = blockIdx.x * 4 + wave;

  const float4* av = (const float4*)(anchor   + (size_t)r * D_DIM) + lane * 2;
  const float4* pv = (const float4*)(positive + (size_t)r * D_DIM) + lane * 2;
  float4 a0 = av[0], a1 = av[1];
  float4 p0 = pv[0], p1 = pv[1];

  float sa = a0.x*a0.x + a0.y*a0.y + a0.z*a0.z + a0.w*a0.w
           + a1.x*a1.x + a1.y*a1.y + a1.z*a1.z + a1.w*a1.w;
  float sp = p0.x*p0.x + p0.y*p0.y + p0.z*p0.z + p0.w*p0.w
           + p1.x*p1.x + p1.y*p1.y + p1.z*p1.z + p1.w*p1.w;
  float dp = a0.x*p0.x + a0.y*p0.y + a0.z*p0.z + a0.w*p0.w
           + a1.x*p1.x + a1.y*p1.y + a1.z*p1.z + a1.w*p1.w;

#pragma unroll
  for (int d = 1; d < 64; d <<= 1) {
    sa += __shfl_xor(sa, d);
    sp += __shfl_xor(sp, d);
    dp += __shfl_xor(dp, d);
  }

  const float na = sqrtf(sa), np = sqrtf(sp);
  const float ia = 1.0f / na, ip = 1.0f / np;

  float na0 = a0.x*ia, na1 = a0.y*ia, na2 = a0.z*ia, na3 = a0.w*ia;
  float na4 = a1.x*ia, na5 = a1.y*ia, na6 = a1.z*ia, na7 = a1.w*ia;
  float np0 = p0.x*ip, np1 = p0.y*ip, np2 = p0.z*ip, np3 = p0.w*ip;
  float np4 = p1.x*ip, np5 = p1.y*ip, np6 = p1.z*ip, np7 = p1.w*ip;

  uint32_t aw0 = __builtin_amdgcn_cvt_pk_fp8_f32(na0, na1, 0,  false);
  aw0          = __builtin_amdgcn_cvt_pk_fp8_f32(na2, na3, aw0, true);
  uint32_t aw1 = __builtin_amdgcn_cvt_pk_fp8_f32(na4, na5, 0,  false);
  aw1          = __builtin_amdgcn_cvt_pk_fp8_f32(na6, na7, aw1, true);
  uint32_t pw0 = __builtin_amdgcn_cvt_pk_fp8_f32(np0, np1, 0,  false);
  pw0          = __builtin_amdgcn_cvt_pk_fp8_f32(np2, np3, pw0, true);
  uint32_t pw1 = __builtin_amdgcn_cvt_pk_fp8_f32(np4, np5, 0,  false);
  pw1          = __builtin_amdgcn_cvt_pk_fp8_f32(np6, np7, pw1, true);

  ((uint2*)a8)[(size_t)r * 64 + lane] = make_uint2(aw0, aw1);
  ((uint2*)p8)[(size_t)r * 64 + lane] = make_uint2(pw0, pw1);

  if (lane == 0) {
    cos_ap[r] = dp / fmaxf(na * np, 1e-8f);
    minenc[r] = 0xFFFFFFFFu;   // +inf in monotone encoding
  }
}

// ---------------------------------------------------------------------------
// global -> LDS direct load, 16B per lane (dest = wave-uniform base + lane*16).
// ---------------------------------------------------------------------------
__device__ __forceinline__ void load16_to_lds(const void* g, void* l) {
  __builtin_amdgcn_global_load_lds(
      (__attribute__((address_space(1))) uint32_t*)(uintptr_t)(g),
      (__attribute__((address_space(3))) uint32_t*)(uintptr_t)(l),
      16, 0, 0);
}

// ---------------------------------------------------------------------------
// Kernel 2: 128x128 fp8 MX-MFMA tile of sim = A_n * P_n^T (scale=1.0), fused
// diagonal-masked row-min -> device atomicMin on encoded floats.
// Double-buffered LDS, one barrier per K-iter.
// Block swizzle: xcd = bid&7 owns A-rowTiles [xcd*8, xcd*8+8) for ALL 64
// colTiles (A stays L2-resident: 512 KB/XCD; P streams once: 4 MB/XCD).
// Cuts L2-fill traffic ~512 MB -> ~36 MB; R3 evidence says we were
// Infinity-Cache-BW bound (~8.6 TB/s sustained), not pipeline bound.
// ---------------------------------------------------------------------------
__global__ __launch_bounds__(256, 2) void simmin_kernel(
    const uint8_t* __restrict__ a8, const uint8_t* __restrict__ p8,
    uint32_t* __restrict__ minenc)
{
  __shared__ __attribute__((aligned(16))) uint8_t Alds[2][128 * 128];
  __shared__ __attribute__((aligned(16))) uint8_t Plds[2][128 * 128];
  __shared__ float redmin[256];

  const int tid  = threadIdx.x;
  const int lane = tid & 63;
  const int wave = tid >> 6;
  const int waveM = wave >> 1, waveN = wave & 1;
  const int quad = lane >> 4;
  const int l15  = lane & 15;

  // super-tile swizzle (see header comment)
  const int bid = blockIdx.x;
  const int blockRow = (bid & 7) * 8 + ((bid >> 3) & 7);
  const int blockCol = bid >> 6;

  f32x4 acc[4][4];
  const f32x4 zero = {0.f, 0.f, 0.f, 0.f};
#pragma unroll
  for (int i = 0; i < 4; i++)
#pragma unroll
    for (int j = 0; j < 4; j++) acc[i][j] = zero;

  // staging: chunk = 8 rows x 128B; lane i: row = i/8, XOR-swizzled k-slot
  // fetched pre-swizzled on the global side (LDS side must stay contiguous).
  const int srow = lane >> 3;
  const int sk   = (lane & 7) ^ srow;
  const uint8_t* aBase = a8 + (size_t)(blockRow * 128) * D_DIM;
  const uint8_t* pBase = p8 + (size_t)(blockCol * 128) * D_DIM;

  auto stage = [&](int k0, int buf) {
#pragma unroll
    for (int c = 0; c < 4; c++) {
      const int chunk = wave * 4 + c;       // 0..15
      const size_t goff = (size_t)(chunk * 8 + srow) * D_DIM + k0 + sk * 16;
      load16_to_lds(aBase + goff, &Alds[buf][chunk * 1024]);
      load16_to_lds(pBase + goff, &Plds[buf][chunk * 1024]);
    }
  };

  stage(0, 0);

#pragma unroll
  for (int k = 0; k < 4; k++) {
    __syncthreads();  // drains loads->buf[k&1]; also fences reads of buf from k-2
    const int buf = k & 1;

    i32x8 af[4], bfr[4];
#pragma unroll
    for (int mf = 0; mf < 4; mf++) {
      const int r = waveM * 64 + mf * 16 + l15;
      const int rx = r & 7;
      const int4 lo = *(const int4*)&Alds[buf][r * 128 + (((quad * 2 + 0) ^ rx) * 16)];
      const int4 hi = *(const int4*)&Alds[buf][r * 128 + (((quad * 2 + 1) ^ rx) * 16)];
      af[mf] = (i32x8){lo.x, lo.y, lo.z, lo.w, hi.x, hi.y, hi.z, hi.w};
    }
#pragma unroll
    for (int nf = 0; nf < 4; nf++) {
      const int r = waveN * 64 + nf * 16 + l15;
      const int rx = r & 7;
      const int4 lo = *(const int4*)&Plds[buf][r * 128 + (((quad * 2 + 0) ^ rx) * 16)];
      const int4 hi = *(const int4*)&Plds[buf][r * 128 + (((quad * 2 + 1) ^ rx) * 16)];
      bfr[nf] = (i32x8){lo.x, lo.y, lo.z, lo.w, hi.x, hi.y, hi.z, hi.w};
    }

    if (k < 3) stage((k + 1) * 128, (k + 1) & 1);  // prefetch next tile

#pragma unroll
    for (int mf = 0; mf < 4; mf++)
#pragma unroll
      for (int nf = 0; nf < 4; nf++)
        acc[mf][nf] = __builtin_amdgcn_mfma_scale_f32_16x16x128_f8f6f4(
            af[mf], bfr[nf], acc[mf][nf],
            0, 0,                 // cbsz=fp8(e4m3) A, blgp=fp8(e4m3) B
            0, 0x7F7F7F7F,        // scale A (2^0)
            0, 0x7F7F7F7F);       // scale B (2^0)
  }

  // ---- fused epilogue: per-row min over this block's 128 cols, diag masked
  const int rowTileBase = blockRow * 128 + waveM * 64;
  const int colTileBase = blockCol * 128 + waveN * 64;

  float rm[4][4];
#pragma unroll
  for (int mf = 0; mf < 4; mf++)
#pragma unroll
    for (int r = 0; r < 4; r++) rm[mf][r] = 3.0e38f;

#pragma unroll
  for (int mf = 0; mf < 4; mf++) {
#pragma unroll
    for (int nf = 0; nf < 4; nf++) {
      const int col = colTileBase + nf * 16 + l15;
#pragma unroll
      for (int r = 0; r < 4; r++) {
        const int row = rowTileBase + mf * 16 + quad * 4 + r;
        const float v = acc[mf][nf][r];
        rm[mf][r] = (row == col) ? rm[mf][r] : fminf(rm[mf][r], v);
      }
    }
  }
#pragma unroll
  for (int d = 1; d < 16; d <<= 1)
#pragma unroll
    for (int mf = 0; mf < 4; mf++)
#pragma unroll
      for (int r = 0; r < 4; r++)
        rm[mf][r] = fminf(rm[mf][r], __shfl_xor(rm[mf][r], d));

  if (l15 == 0) {
#pragma unroll
    for (int mf = 0; mf < 4; mf++)
#pragma unroll
      for (int r = 0; r < 4; r++)
        redmin[waveN * 128 + waveM * 64 + mf * 16 + quad * 4 + r] = rm[mf][r];
  }
  __syncthreads();

  if (tid < 128) {
    const float m = fminf(redmin[tid], redmin[128 + tid]);
    atomicMin(&minenc[blockRow * 128 + tid], enc_f32(m));  // device-scope
  }
}

// ---------------------------------------------------------------------------
// Kernel 3: single block (1024 thr) — decode row-mins, loss, mean, store.
// ---------------------------------------------------------------------------
__global__ __launch_bounds__(1024) void finalize_kernel(
    const uint32_t* __restrict__ minenc, const float* __restrict__ cos_ap,
    float* __restrict__ out)
{
  float sum = 0.0f;
#pragma unroll
  for (int r = threadIdx.x; r < B_ROWS; r += 1024)
    sum += fmaxf(0.0f, 1.0f + cos_ap[r] - dec_f32(minenc[r]));

#pragma unroll
  for (int d = 1; d < 64; d <<= 1) sum += __shfl_xor(sum, d);
  __shared__ float s[16];
  if ((threadIdx.x & 63) == 0) s[threadIdx.x >> 6] = sum;
  __syncthreads();
  if (threadIdx.x < 64) {
    float t = (threadIdx.x < 16) ? s[threadIdx.x] : 0.0f;
#pragma unroll
    for (int d = 1; d < 16; d <<= 1) t += __shfl_xor(t, d);
    if (threadIdx.x == 0) out[0] = t * (1.0f / (float)B_ROWS);
  }
}

// ---------------------------------------------------------------------------
extern "C" void kernel_launch(void* const* d_in, const int* in_sizes, int n_in,
                              void* d_out, int out_size, void* d_ws, size_t ws_size,
                              hipStream_t stream) {
  const float* anchor   = (const float*)d_in[0];
  const float* positive = (const float*)d_in[1];

  char* ws = (char*)d_ws;
  uint32_t* a8     = (uint32_t*)(ws);                                // 4 MB
  uint32_t* p8     = (uint32_t*)(ws + (4ull << 20));                 // 4 MB
  float*    cos_ap = (float*)(ws + (8ull << 20));                    // 32 KB
  uint32_t* minenc = (uint32_t*)(ws + (8ull << 20) + (32ull << 10)); // 32 KB
  float*    out = (float*)d_out;

  norm_kernel<<<B_ROWS / 4, 256, 0, stream>>>(anchor, positive, a8, p8,
                                              cos_ap, minenc);
  simmin_kernel<<<4096, 256, 0, stream>>>((const uint8_t*)a8,
                                          (const uint8_t*)p8, minenc);
  finalize_kernel<<<1, 1024, 0, stream>>>(minenc, cos_ap, out);
}